// Round 11
// baseline (158.407 us; speedup 1.0000x reference)
//
#include <hip/hip_runtime.h>

#define F_IN 32
#define HID 16
#define BSHIFT 6                 // 64 dst-nodes per bucket (R4-verified best)
#define BNODES (1 << BSHIFT)     // 64
#define CAP 1440                 // slots/bucket: mean 1024, sigma 32 -> +13 sigma
#define NBINS 2048               // bucket bins (nbuckets=1563 <= 2048)
#define CHUNK 2048               // R11: 8192->2048. 782 partition blocks (was 196,
                                 // <1 block/CU -- no latency hiding for the
                                 // LDS-atomic + scattered-store chains)
#define SRCM 0x1FFFFu
#define WS2 17                   // padded stride W2_l/W2_r (16+1)

typedef unsigned u32x2 __attribute__((ext_vector_type(2)));
typedef unsigned u32x4 __attribute__((ext_vector_type(4)));
typedef float f32x4 __attribute__((ext_vector_type(4)));

// Non-temporal stores on later-gathered tensors (R10: neutral, kept — they
// can only reduce dirty-line lingering in producer XCD L2s).
__device__ __forceinline__ void nt_store4(unsigned* p, unsigned a, unsigned b,
                                          unsigned c, unsigned d) {
    u32x4 v = {a, b, c, d};
    __builtin_nontemporal_store(v, (u32x4*)p);
}
__device__ __forceinline__ void nt_store2(unsigned* p, unsigned a, unsigned b) {
    u32x2 v = {a, b};
    __builtin_nontemporal_store(v, (u32x2*)p);
}
__device__ __forceinline__ void nt_storef4(float* p, float a, float b,
                                           float c, float d) {
    f32x4 v = {a, b, c, d};
    __builtin_nontemporal_store(v, (f32x4*)p);
}

__device__ __forceinline__ void add4(float4& a, const float4& b) {
    a.x += b.x; a.y += b.y; a.z += b.z; a.w += b.w;
}
__device__ __forceinline__ unsigned pack2(float a, float b) {
    unsigned ua = __float_as_uint(a);
    unsigned ub = __float_as_uint(b);
    ua = (ua + 0x7FFFu + ((ua >> 16) & 1u)) >> 16;
    ub = (ub + 0x7FFFu + ((ub >> 16) & 1u)) >> 16;
    return ua | (ub << 16);
}
__device__ __forceinline__ float lo2f(unsigned u) { return __uint_as_float(u << 16); }
__device__ __forceinline__ float hi2f(unsigned u) { return __uint_as_float(u & 0xFFFF0000u); }
__device__ __forceinline__ float4 unp(uint2 v) {
    return make_float4(lo2f(v.x), hi2f(v.x), lo2f(v.y), hi2f(v.y));
}

// ---------------------------------------------------------------------------
// Fat kernel (R10-verified; only CHUNK changed):
//  Blocks [0, nodeBlocks): y1 = x@W1_l^T (bf16) AND y1r = x@W1_r^T + b1 (fp32).
//  Blocks [nodeBlocks,...): LDS-hist multisplit, block-contiguous bucket runs
//  (settled: per-record global append ping-pongs lines across non-coherent
//  XCD L2s -- R5: 107MB, R7: 89MB WRITE_SIZE).
// ---------------------------------------------------------------------------
__global__ void __launch_bounds__(256) k_pre(const float* __restrict__ x,
                                             const float* __restrict__ W1_l,
                                             const float* __restrict__ b1,
                                             const float* __restrict__ W1_r,
                                             unsigned* __restrict__ y1b,
                                             float* __restrict__ y1r,
                                             const int* __restrict__ ei,
                                             int* __restrict__ bucketCursor,
                                             unsigned* __restrict__ bucketBuf,
                                             int N, int E, int nodeBlocks) {
    __shared__ int cnt[NBINS];      // histogram, then reused as running cursor
    __shared__ int runBase[NBINS];
    __shared__ float Wa[HID * F_IN];
    __shared__ float Wb[HID * F_IN];
    __shared__ float bb[HID];
    int tid = threadIdx.x;

    if ((int)blockIdx.x < nodeBlocks) {
        // ---- y1 + y1r job ----
        for (int i = tid; i < HID * F_IN; i += 256) { Wa[i] = W1_l[i]; Wb[i] = W1_r[i]; }
        if (tid < HID) bb[tid] = b1[tid];
        __syncthreads();
        int node = blockIdx.x * 256 + tid;
        if (node >= N) return;
        float xr[F_IN];
        const float4* xp = (const float4*)(x + (size_t)node * F_IN);
#pragma unroll
        for (int i = 0; i < F_IN / 4; i++) {
            float4 v = xp[i];
            xr[4 * i + 0] = v.x; xr[4 * i + 1] = v.y;
            xr[4 * i + 2] = v.z; xr[4 * i + 3] = v.w;
        }
        float a[HID];
#pragma unroll
        for (int o = 0; o < HID; o++) {
            float s = 0.f;
#pragma unroll
            for (int k = 0; k < F_IN; k++) s += xr[k] * Wa[o * F_IN + k];
            a[o] = s;
        }
        unsigned* yp = y1b + (size_t)node * 8;
        nt_store4(yp, pack2(a[0], a[1]), pack2(a[2], a[3]),
                  pack2(a[4], a[5]), pack2(a[6], a[7]));
        nt_store4(yp + 4, pack2(a[8], a[9]), pack2(a[10], a[11]),
                  pack2(a[12], a[13]), pack2(a[14], a[15]));
#pragma unroll
        for (int o = 0; o < HID; o++) {
            float s = bb[o];
#pragma unroll
            for (int k = 0; k < F_IN; k++) s += xr[k] * Wb[o * F_IN + k];
            a[o] = s;
        }
        float* rp = y1r + (size_t)node * HID;
        nt_storef4(rp + 0,  a[0],  a[1],  a[2],  a[3]);
        nt_storef4(rp + 4,  a[4],  a[5],  a[6],  a[7]);
        nt_storef4(rp + 8,  a[8],  a[9],  a[10], a[11]);
        nt_storef4(rp + 12, a[12], a[13], a[14], a[15]);
        return;
    }

    // ---- partition job (R1/R4-verified multisplit, unchanged) ----
    int pb = blockIdx.x - nodeBlocks;
    int e0 = pb * CHUNK;
    int e1 = min(e0 + CHUNK, E);
    int n4 = (e1 - e0) >> 2;                       // E, CHUNK multiples of 4
    const int4* dst4 = (const int4*)(ei + E + e0);
    const int4* src4 = (const int4*)(ei + e0);

#pragma unroll
    for (int i = 0; i < NBINS / 256; i++) cnt[tid + 256 * i] = 0;
    __syncthreads();
    for (int i = tid; i < n4; i += 256) {
        int4 d = dst4[i];
        atomicAdd(&cnt[d.x >> BSHIFT], 1);
        atomicAdd(&cnt[d.y >> BSHIFT], 1);
        atomicAdd(&cnt[d.z >> BSHIFT], 1);
        atomicAdd(&cnt[d.w >> BSHIFT], 1);
    }
    __syncthreads();
#pragma unroll
    for (int i = 0; i < NBINS / 256; i++) {
        int b = tid + 256 * i;
        int c = cnt[b];
        runBase[b] = c ? atomicAdd(&bucketCursor[b], c) : 0;
        cnt[b] = 0;                                 // becomes running cursor
    }
    __syncthreads();
    for (int i = tid; i < n4; i += 256) {
        int4 d = dst4[i];
        int4 s = src4[i];
        {
            int b = d.x >> BSHIFT;
            int pos = runBase[b] + atomicAdd(&cnt[b], 1);
            if (pos < CAP)
                bucketBuf[(size_t)b * CAP + pos] = ((unsigned)(d.x & (BNODES - 1)) << 17) | (unsigned)s.x;
        }
        {
            int b = d.y >> BSHIFT;
            int pos = runBase[b] + atomicAdd(&cnt[b], 1);
            if (pos < CAP)
                bucketBuf[(size_t)b * CAP + pos] = ((unsigned)(d.y & (BNODES - 1)) << 17) | (unsigned)s.y;
        }
        {
            int b = d.z >> BSHIFT;
            int pos = runBase[b] + atomicAdd(&cnt[b], 1);
            if (pos < CAP)
                bucketBuf[(size_t)b * CAP + pos] = ((unsigned)(d.z & (BNODES - 1)) << 17) | (unsigned)s.z;
        }
        {
            int b = d.w >> BSHIFT;
            int pos = runBase[b] + atomicAdd(&cnt[b], 1);
            if (pos < CAP)
                bucketBuf[(size_t)b * CAP + pos] = ((unsigned)(d.w & (BNODES - 1)) << 17) | (unsigned)s.w;
        }
    }
}

// ---------------------------------------------------------------------------
// Fused layer 1 (R10-verified, unchanged): one block per bucket of 64 nodes.
// Stage raw records -> in-LDS counting sort -> persist sorted srcs + offsets
// -> slot aggregation -> h = relu(mean + y1r) -> bf16 (nt store).
// ---------------------------------------------------------------------------
__global__ void __launch_bounds__(256) k_agg1f(const unsigned* __restrict__ y1b,
                                               const float* __restrict__ y1r,
                                               unsigned* __restrict__ bucketBuf,
                                               const int* __restrict__ bucketCursor,
                                               unsigned* __restrict__ hb,
                                               int* __restrict__ meta, int N) {
    __shared__ __align__(16) unsigned sA[CAP];    // raw records
    __shared__ __align__(16) unsigned sB[CAP];    // sorted src
    __shared__ int hist[BNODES];
    __shared__ int scn[BNODES];
    __shared__ int cur[BNODES];
    int tid = threadIdx.x, b = blockIdx.x;

    if (tid < BNODES) hist[tid] = 0;
    int nRec = min(bucketCursor[b], CAP);
    unsigned* buf = bucketBuf + (size_t)b * CAP;
    int n4s = (nRec + 3) >> 2;                    // uint4 staging (tail garbage OK)
    for (int i = tid; i < n4s; i += 256)
        ((uint4*)sA)[i] = ((const uint4*)buf)[i];
    __syncthreads();
    for (int i = tid; i < nRec; i += 256) atomicAdd(&hist[sA[i] >> 17], 1);
    __syncthreads();
    if (tid < BNODES) scn[tid] = hist[tid];
    __syncthreads();
    for (int off = 1; off < BNODES; off <<= 1) {
        int v = (tid < BNODES && tid >= off) ? scn[tid - off] : 0;
        __syncthreads();
        if (tid < BNODES && tid >= off) scn[tid] += v;
        __syncthreads();
    }
    if (tid < BNODES) cur[tid] = scn[tid] - hist[tid];
    __syncthreads();
    for (int i = tid; i < nRec; i += 256) {
        unsigned r = sA[i];
        int pos = atomicAdd(&cur[r >> 17], 1);
        sB[pos] = r & SRCM;
    }
    __syncthreads();

    // persist sorted order so k_l2f skips the sort entirely.
    for (int i = tid; i < n4s; i += 256)
        ((uint4*)buf)[i] = ((const uint4*)sB)[i];
    if (tid < BNODES) {
        meta[(size_t)b * 128 + tid] = scn[tid] - hist[tid];          // start
        meta[(size_t)b * 128 + BNODES + tid] = scn[tid];             // end
    }

    const uint2* yv = (const uint2*)y1b;
    {
        int nl = tid >> 2, c = tid & 3;
        int node = b * BNODES + nl;
        if (node < N) {
            int start = scn[nl] - hist[nl];
            int dg = hist[nl];
            int jend = start + dg;
            float4 a0 = make_float4(0, 0, 0, 0), a1 = a0;
            int j = start;
            for (; j + 4 <= jend; j += 4) {
                unsigned s0 = sB[j], s1 = sB[j + 1], s2 = sB[j + 2], s3 = sB[j + 3];
                uint2 v0 = yv[(size_t)s0 * 4 + c];
                uint2 v1 = yv[(size_t)s1 * 4 + c];
                uint2 v2 = yv[(size_t)s2 * 4 + c];
                uint2 v3 = yv[(size_t)s3 * 4 + c];
                add4(a0, unp(v0)); add4(a1, unp(v1));
                add4(a0, unp(v2)); add4(a1, unp(v3));
            }
            for (; j < jend; j++) {
                uint2 v = yv[(size_t)sB[j] * 4 + c];
                add4(a0, unp(v));
            }
            add4(a0, a1);
            float inv = 1.0f / (float)(dg > 0 ? dg : 1);
            float4 r4 = ((const float4*)(y1r + (size_t)node * HID))[c];   // x@W1_r^T + b1
            float o0 = fmaxf(a0.x * inv + r4.x, 0.0f);
            float o1 = fmaxf(a0.y * inv + r4.y, 0.0f);
            float o2 = fmaxf(a0.z * inv + r4.z, 0.0f);
            float o3 = fmaxf(a0.w * inv + r4.w, 0.0f);
            nt_store2(hb + (size_t)node * 8 + c * 2, pack2(o0, o1), pack2(o2, o3));
        }
    }
}

// ---------------------------------------------------------------------------
// Fused layer 2 (R10-verified, unchanged): NO sort — reads sorted srcs +
// per-node offsets persisted by k_agg1f. Aggregate h, exchange mean chunks
// via LDS, epilogue out = m @ W2_l^T + b2 + h @ W2_r^T (fp32).
// ---------------------------------------------------------------------------
__global__ void __launch_bounds__(256) k_l2f(const unsigned* __restrict__ hb,
                                             const unsigned* __restrict__ bucketBuf,
                                             const int* __restrict__ bucketCursor,
                                             const int* __restrict__ meta,
                                             const float* __restrict__ W2_l,
                                             const float* __restrict__ b2,
                                             const float* __restrict__ W2_r,
                                             float* __restrict__ out, int N) {
    __shared__ __align__(16) unsigned sB[CAP];    // sorted src
    __shared__ int s0[BNODES];                    // start offsets
    __shared__ int s1[BNODES];                    // end offsets
    __shared__ float mm[BNODES * (HID + 1)];      // per-node means (padded)
    __shared__ float Wl[F_IN * WS2];
    __shared__ float Wr[F_IN * WS2];
    __shared__ float bs[F_IN];
    int tid = threadIdx.x, b = blockIdx.x;

    for (int i = tid; i < F_IN * HID; i += 256) {
        int r = i >> 4, q = i & 15;
        Wl[r * WS2 + q] = W2_l[i];
        Wr[r * WS2 + q] = W2_r[i];
    }
    if (tid < F_IN) bs[tid] = b2[tid];
    if (tid < BNODES) {
        s0[tid] = meta[(size_t)b * 128 + tid];
        s1[tid] = meta[(size_t)b * 128 + BNODES + tid];
    }
    int nRec = min(bucketCursor[b], CAP);
    const uint4* bv = (const uint4*)(bucketBuf + (size_t)b * CAP);
    int n4s = (nRec + 3) >> 2;
    for (int i = tid; i < n4s; i += 256) ((uint4*)sB)[i] = bv[i];
    __syncthreads();

    const uint2* hv = (const uint2*)hb;
    {
        int nl = tid >> 2, c = tid & 3;
        int node = b * BNODES + nl;
        if (node < N) {
            int start = s0[nl];
            int jend = s1[nl];
            int dg = jend - start;
            float4 a0 = make_float4(0, 0, 0, 0), a1 = a0;
            int j = start;
            for (; j + 4 <= jend; j += 4) {
                unsigned v0i = sB[j], v1i = sB[j + 1], v2i = sB[j + 2], v3i = sB[j + 3];
                uint2 v0 = hv[(size_t)v0i * 4 + c];
                uint2 v1 = hv[(size_t)v1i * 4 + c];
                uint2 v2 = hv[(size_t)v2i * 4 + c];
                uint2 v3 = hv[(size_t)v3i * 4 + c];
                add4(a0, unp(v0)); add4(a1, unp(v1));
                add4(a0, unp(v2)); add4(a1, unp(v3));
            }
            for (; j < jend; j++) {
                uint2 v = hv[(size_t)sB[j] * 4 + c];
                add4(a0, unp(v));
            }
            add4(a0, a1);
            float inv = 1.0f / (float)(dg > 0 ? dg : 1);
            mm[nl * (HID + 1) + c * 4 + 0] = a0.x * inv;
            mm[nl * (HID + 1) + c * 4 + 1] = a0.y * inv;
            mm[nl * (HID + 1) + c * 4 + 2] = a0.z * inv;
            mm[nl * (HID + 1) + c * 4 + 3] = a0.w * inv;
        }
    }
    __syncthreads();

    // epilogue: slot (node, c) computes outputs o = c*8 .. c*8+7
    {
        int nl = tid >> 2, c = tid & 3;
        int node = b * BNODES + nl;
        if (node >= N) return;

        float m[HID];
#pragma unroll
        for (int k = 0; k < HID; k++) m[k] = mm[nl * (HID + 1) + k];

        float hr[HID];
        const uint4* hp = (const uint4*)(hb + (size_t)node * 8);
        uint4 u0 = hp[0], u1 = hp[1];
        hr[0] = lo2f(u0.x); hr[1] = hi2f(u0.x); hr[2] = lo2f(u0.y); hr[3] = hi2f(u0.y);
        hr[4] = lo2f(u0.z); hr[5] = hi2f(u0.z); hr[6] = lo2f(u0.w); hr[7] = hi2f(u0.w);
        hr[8] = lo2f(u1.x); hr[9] = hi2f(u1.x); hr[10] = lo2f(u1.y); hr[11] = hi2f(u1.y);
        hr[12] = lo2f(u1.z); hr[13] = hi2f(u1.z); hr[14] = lo2f(u1.w); hr[15] = hi2f(u1.w);

        float a[8];
#pragma unroll
        for (int jj = 0; jj < 8; jj++) {
            int o = c * 8 + jj;
            float s = bs[o];
#pragma unroll
            for (int k = 0; k < HID; k++)
                s += m[k] * Wl[o * WS2 + k] + hr[k] * Wr[o * WS2 + k];
            a[jj] = s;
        }
        float4* op = (float4*)(out + (size_t)node * F_IN + c * 8);
        op[0] = make_float4(a[0], a[1], a[2], a[3]);
        op[1] = make_float4(a[4], a[5], a[6], a[7]);
    }
}

extern "C" void kernel_launch(void* const* d_in, const int* in_sizes, int n_in,
                              void* d_out, int out_size, void* d_ws, size_t ws_size,
                              hipStream_t stream) {
    const float* x    = (const float*)d_in[0];
    const int*   ei   = (const int*)d_in[1];   // [2, E] int32
    const float* W1_l = (const float*)d_in[2];
    const float* b1   = (const float*)d_in[3];
    const float* W1_r = (const float*)d_in[4];
    const float* W2_l = (const float*)d_in[5];
    const float* b2   = (const float*)d_in[6];
    const float* W2_r = (const float*)d_in[7];
    float* out = (float*)d_out;

    const int N = in_sizes[0] / F_IN;
    const int E = in_sizes[1] / 2;
    const int nbuckets = (N + BNODES - 1) >> BSHIFT;     // 1563 for N=100000

    int* bucketCursor = (int*)d_ws;                        // [NBINS]
    unsigned* bucketBuf = (unsigned*)(bucketCursor + NBINS);// [nbuckets * CAP]
    unsigned* y1b = bucketBuf + (size_t)nbuckets * CAP;    // [N * 8]  bf16 packed
    unsigned* hb  = y1b + (size_t)N * 8;                   // [N * 8]  bf16 packed
    int* meta = (int*)(hb + (size_t)N * 8);                // [nbuckets * 128]
    float* y1r = (float*)(meta + (size_t)nbuckets * 128);  // [N * 16] fp32

    hipMemsetAsync(bucketCursor, 0, NBINS * sizeof(int), stream);

    const int nodeBlocks = (N + 255) / 256;                // 391
    const int partBlocks = (E + CHUNK - 1) / CHUNK;        // 782

    k_pre<<<nodeBlocks + partBlocks, 256, 0, stream>>>(x, W1_l, b1, W1_r,
                                                       y1b, y1r, ei,
                                                       bucketCursor, bucketBuf,
                                                       N, E, nodeBlocks);
    k_agg1f<<<nbuckets, 256, 0, stream>>>(y1b, y1r, bucketBuf, bucketCursor,
                                          hb, meta, N);
    k_l2f<<<nbuckets, 256, 0, stream>>>(hb, bucketBuf, bucketCursor, meta,
                                        W2_l, b2, W2_r, out, N);
}

// Round 13
// 147.044 us; speedup vs baseline: 1.0773x; 1.0773x over previous
//
#include <hip/hip_runtime.h>

#define F_IN 32
#define HID 16
#define BSHIFT 6                 // 64 dst-nodes per bucket (R4-verified best)
#define BNODES (1 << BSHIFT)     // 64
#define CAP 1440                 // slots/bucket: mean 1024, sigma 32 -> +13 sigma
#define NBINS 2048               // bucket bins (nbuckets=1563 <= 2048)
#define CHUNK 8192               // edges per partition block (measured sweet spot:
                                 // 2048 -> +10us per-block bin overhead (R11);
                                 // >8192 -> partition tail doubles (<1 block/CU))
#define SRCM 0x1FFFFu
#define WS2 17                   // padded stride W2_l/W2_r (16+1)

__device__ __forceinline__ void add4(float4& a, const float4& b) {
    a.x += b.x; a.y += b.y; a.z += b.z; a.w += b.w;
}
__device__ __forceinline__ unsigned pack2(float a, float b) {
    unsigned ua = __float_as_uint(a);
    unsigned ub = __float_as_uint(b);
    ua = (ua + 0x7FFFu + ((ua >> 16) & 1u)) >> 16;
    ub = (ub + 0x7FFFu + ((ub >> 16) & 1u)) >> 16;
    return ua | (ub << 16);
}
__device__ __forceinline__ float lo2f(unsigned u) { return __uint_as_float(u << 16); }
__device__ __forceinline__ float hi2f(unsigned u) { return __uint_as_float(u & 0xFFFF0000u); }
__device__ __forceinline__ float4 unp(uint2 v) {
    return make_float4(lo2f(v.x), hi2f(v.x), lo2f(v.y), hi2f(v.y));
}

// ---------------------------------------------------------------------------
// Fat kernel (R4-verified, 147.65us best):
//  Blocks [0, nodeBlocks): y1 = x@W1_l^T (bf16) AND y1r = x@W1_r^T + b1 (fp32).
//  Blocks [nodeBlocks,...): LDS-hist multisplit, block-contiguous bucket runs
//  (settled invariant: per-record global append ping-pongs lines across
//  non-coherent XCD L2s -- R5: 107MB, R7: 89MB WRITE_SIZE).
// ---------------------------------------------------------------------------
__global__ void __launch_bounds__(256) k_pre(const float* __restrict__ x,
                                             const float* __restrict__ W1_l,
                                             const float* __restrict__ b1,
                                             const float* __restrict__ W1_r,
                                             unsigned* __restrict__ y1b,
                                             float* __restrict__ y1r,
                                             const int* __restrict__ ei,
                                             int* __restrict__ bucketCursor,
                                             unsigned* __restrict__ bucketBuf,
                                             int N, int E, int nodeBlocks) {
    __shared__ int cnt[NBINS];      // histogram, then reused as running cursor
    __shared__ int runBase[NBINS];
    __shared__ float Wa[HID * F_IN];
    __shared__ float Wb[HID * F_IN];
    __shared__ float bb[HID];
    int tid = threadIdx.x;

    if ((int)blockIdx.x < nodeBlocks) {
        // ---- y1 + y1r job ----
        for (int i = tid; i < HID * F_IN; i += 256) { Wa[i] = W1_l[i]; Wb[i] = W1_r[i]; }
        if (tid < HID) bb[tid] = b1[tid];
        __syncthreads();
        int node = blockIdx.x * 256 + tid;
        if (node >= N) return;
        float xr[F_IN];
        const float4* xp = (const float4*)(x + (size_t)node * F_IN);
#pragma unroll
        for (int i = 0; i < F_IN / 4; i++) {
            float4 v = xp[i];
            xr[4 * i + 0] = v.x; xr[4 * i + 1] = v.y;
            xr[4 * i + 2] = v.z; xr[4 * i + 3] = v.w;
        }
        float a[HID];
#pragma unroll
        for (int o = 0; o < HID; o++) {
            float s = 0.f;
#pragma unroll
            for (int k = 0; k < F_IN; k++) s += xr[k] * Wa[o * F_IN + k];
            a[o] = s;
        }
        uint4* yp = (uint4*)(y1b + (size_t)node * 8);
        yp[0] = make_uint4(pack2(a[0], a[1]), pack2(a[2], a[3]),
                           pack2(a[4], a[5]), pack2(a[6], a[7]));
        yp[1] = make_uint4(pack2(a[8], a[9]), pack2(a[10], a[11]),
                           pack2(a[12], a[13]), pack2(a[14], a[15]));
#pragma unroll
        for (int o = 0; o < HID; o++) {
            float s = bb[o];
#pragma unroll
            for (int k = 0; k < F_IN; k++) s += xr[k] * Wb[o * F_IN + k];
            a[o] = s;
        }
        float4* rp = (float4*)(y1r + (size_t)node * HID);
        rp[0] = make_float4(a[0], a[1], a[2], a[3]);
        rp[1] = make_float4(a[4], a[5], a[6], a[7]);
        rp[2] = make_float4(a[8], a[9], a[10], a[11]);
        rp[3] = make_float4(a[12], a[13], a[14], a[15]);
        return;
    }

    // ---- partition job (R1/R4-verified multisplit) ----
    int pb = blockIdx.x - nodeBlocks;
    int e0 = pb * CHUNK;
    int e1 = min(e0 + CHUNK, E);
    int n4 = (e1 - e0) >> 2;                       // E, CHUNK multiples of 4
    const int4* dst4 = (const int4*)(ei + E + e0);
    const int4* src4 = (const int4*)(ei + e0);

#pragma unroll
    for (int i = 0; i < NBINS / 256; i++) cnt[tid + 256 * i] = 0;
    __syncthreads();
    for (int i = tid; i < n4; i += 256) {
        int4 d = dst4[i];
        atomicAdd(&cnt[d.x >> BSHIFT], 1);
        atomicAdd(&cnt[d.y >> BSHIFT], 1);
        atomicAdd(&cnt[d.z >> BSHIFT], 1);
        atomicAdd(&cnt[d.w >> BSHIFT], 1);
    }
    __syncthreads();
#pragma unroll
    for (int i = 0; i < NBINS / 256; i++) {
        int b = tid + 256 * i;
        int c = cnt[b];
        runBase[b] = c ? atomicAdd(&bucketCursor[b], c) : 0;
        cnt[b] = 0;                                 // becomes running cursor
    }
    __syncthreads();
    for (int i = tid; i < n4; i += 256) {
        int4 d = dst4[i];
        int4 s = src4[i];
        {
            int b = d.x >> BSHIFT;
            int pos = runBase[b] + atomicAdd(&cnt[b], 1);
            if (pos < CAP)
                bucketBuf[(size_t)b * CAP + pos] = ((unsigned)(d.x & (BNODES - 1)) << 17) | (unsigned)s.x;
        }
        {
            int b = d.y >> BSHIFT;
            int pos = runBase[b] + atomicAdd(&cnt[b], 1);
            if (pos < CAP)
                bucketBuf[(size_t)b * CAP + pos] = ((unsigned)(d.y & (BNODES - 1)) << 17) | (unsigned)s.y;
        }
        {
            int b = d.z >> BSHIFT;
            int pos = runBase[b] + atomicAdd(&cnt[b], 1);
            if (pos < CAP)
                bucketBuf[(size_t)b * CAP + pos] = ((unsigned)(d.z & (BNODES - 1)) << 17) | (unsigned)s.z;
        }
        {
            int b = d.w >> BSHIFT;
            int pos = runBase[b] + atomicAdd(&cnt[b], 1);
            if (pos < CAP)
                bucketBuf[(size_t)b * CAP + pos] = ((unsigned)(d.w & (BNODES - 1)) << 17) | (unsigned)s.w;
        }
    }
}

// ---------------------------------------------------------------------------
// Fused layer 1 (R4-verified): one block per bucket of 64 nodes (256 slots =
// 1 pass). Stage raw records -> in-LDS counting sort -> persist sorted srcs
// + offsets -> slot aggregation -> epilogue h = relu(mean + y1r) -> bf16.
// ---------------------------------------------------------------------------
__global__ void __launch_bounds__(256) k_agg1f(const unsigned* __restrict__ y1b,
                                               const float* __restrict__ y1r,
                                               unsigned* __restrict__ bucketBuf,
                                               const int* __restrict__ bucketCursor,
                                               unsigned* __restrict__ hb,
                                               int* __restrict__ meta, int N) {
    __shared__ __align__(16) unsigned sA[CAP];    // raw records
    __shared__ __align__(16) unsigned sB[CAP];    // sorted src
    __shared__ int hist[BNODES];
    __shared__ int scn[BNODES];
    __shared__ int cur[BNODES];
    int tid = threadIdx.x, b = blockIdx.x;

    if (tid < BNODES) hist[tid] = 0;
    int nRec = min(bucketCursor[b], CAP);
    unsigned* buf = bucketBuf + (size_t)b * CAP;
    int n4s = (nRec + 3) >> 2;                    // uint4 staging (tail garbage OK)
    for (int i = tid; i < n4s; i += 256)
        ((uint4*)sA)[i] = ((const uint4*)buf)[i];
    __syncthreads();
    for (int i = tid; i < nRec; i += 256) atomicAdd(&hist[sA[i] >> 17], 1);
    __syncthreads();
    if (tid < BNODES) scn[tid] = hist[tid];
    __syncthreads();
    for (int off = 1; off < BNODES; off <<= 1) {
        int v = (tid < BNODES && tid >= off) ? scn[tid - off] : 0;
        __syncthreads();
        if (tid < BNODES && tid >= off) scn[tid] += v;
        __syncthreads();
    }
    if (tid < BNODES) cur[tid] = scn[tid] - hist[tid];
    __syncthreads();
    for (int i = tid; i < nRec; i += 256) {
        unsigned r = sA[i];
        int pos = atomicAdd(&cur[r >> 17], 1);
        sB[pos] = r & SRCM;
    }
    __syncthreads();

    // persist sorted order so k_l2f skips the sort entirely.
    for (int i = tid; i < n4s; i += 256)
        ((uint4*)buf)[i] = ((const uint4*)sB)[i];
    if (tid < BNODES) {
        meta[(size_t)b * 128 + tid] = scn[tid] - hist[tid];          // start
        meta[(size_t)b * 128 + BNODES + tid] = scn[tid];             // end
    }

    const uint2* yv = (const uint2*)y1b;
    {
        int nl = tid >> 2, c = tid & 3;
        int node = b * BNODES + nl;
        if (node < N) {
            int start = scn[nl] - hist[nl];
            int dg = hist[nl];
            int jend = start + dg;
            float4 a0 = make_float4(0, 0, 0, 0), a1 = a0;
            int j = start;
            for (; j + 4 <= jend; j += 4) {
                unsigned s0 = sB[j], s1 = sB[j + 1], s2 = sB[j + 2], s3 = sB[j + 3];
                uint2 v0 = yv[(size_t)s0 * 4 + c];
                uint2 v1 = yv[(size_t)s1 * 4 + c];
                uint2 v2 = yv[(size_t)s2 * 4 + c];
                uint2 v3 = yv[(size_t)s3 * 4 + c];
                add4(a0, unp(v0)); add4(a1, unp(v1));
                add4(a0, unp(v2)); add4(a1, unp(v3));
            }
            for (; j < jend; j++) {
                uint2 v = yv[(size_t)sB[j] * 4 + c];
                add4(a0, unp(v));
            }
            add4(a0, a1);
            float inv = 1.0f / (float)(dg > 0 ? dg : 1);
            float4 r4 = ((const float4*)(y1r + (size_t)node * HID))[c];   // x@W1_r^T + b1
            float o0 = fmaxf(a0.x * inv + r4.x, 0.0f);
            float o1 = fmaxf(a0.y * inv + r4.y, 0.0f);
            float o2 = fmaxf(a0.z * inv + r4.z, 0.0f);
            float o3 = fmaxf(a0.w * inv + r4.w, 0.0f);
            ((uint2*)hb)[(size_t)node * 4 + c] = make_uint2(pack2(o0, o1), pack2(o2, o3));
        }
    }
}

// ---------------------------------------------------------------------------
// Fused layer 2 (R4-verified): NO sort — reads the sorted srcs + per-node
// offsets persisted by k_agg1f. Aggregate h, exchange mean chunks via LDS,
// epilogue out = m @ W2_l^T + b2 + h @ W2_r^T (fp32).
// ---------------------------------------------------------------------------
__global__ void __launch_bounds__(256) k_l2f(const unsigned* __restrict__ hb,
                                             const unsigned* __restrict__ bucketBuf,
                                             const int* __restrict__ bucketCursor,
                                             const int* __restrict__ meta,
                                             const float* __restrict__ W2_l,
                                             const float* __restrict__ b2,
                                             const float* __restrict__ W2_r,
                                             float* __restrict__ out, int N) {
    __shared__ __align__(16) unsigned sB[CAP];    // sorted src
    __shared__ int s0[BNODES];                    // start offsets
    __shared__ int s1[BNODES];                    // end offsets
    __shared__ float mm[BNODES * (HID + 1)];      // per-node means (padded)
    __shared__ float Wl[F_IN * WS2];
    __shared__ float Wr[F_IN * WS2];
    __shared__ float bs[F_IN];
    int tid = threadIdx.x, b = blockIdx.x;

    for (int i = tid; i < F_IN * HID; i += 256) {
        int r = i >> 4, q = i & 15;
        Wl[r * WS2 + q] = W2_l[i];
        Wr[r * WS2 + q] = W2_r[i];
    }
    if (tid < F_IN) bs[tid] = b2[tid];
    if (tid < BNODES) {
        s0[tid] = meta[(size_t)b * 128 + tid];
        s1[tid] = meta[(size_t)b * 128 + BNODES + tid];
    }
    int nRec = min(bucketCursor[b], CAP);
    const uint4* bv = (const uint4*)(bucketBuf + (size_t)b * CAP);
    int n4s = (nRec + 3) >> 2;
    for (int i = tid; i < n4s; i += 256) ((uint4*)sB)[i] = bv[i];
    __syncthreads();

    const uint2* hv = (const uint2*)hb;
    {
        int nl = tid >> 2, c = tid & 3;
        int node = b * BNODES + nl;
        if (node < N) {
            int start = s0[nl];
            int jend = s1[nl];
            int dg = jend - start;
            float4 a0 = make_float4(0, 0, 0, 0), a1 = a0;
            int j = start;
            for (; j + 4 <= jend; j += 4) {
                unsigned v0i = sB[j], v1i = sB[j + 1], v2i = sB[j + 2], v3i = sB[j + 3];
                uint2 v0 = hv[(size_t)v0i * 4 + c];
                uint2 v1 = hv[(size_t)v1i * 4 + c];
                uint2 v2 = hv[(size_t)v2i * 4 + c];
                uint2 v3 = hv[(size_t)v3i * 4 + c];
                add4(a0, unp(v0)); add4(a1, unp(v1));
                add4(a0, unp(v2)); add4(a1, unp(v3));
            }
            for (; j < jend; j++) {
                uint2 v = hv[(size_t)sB[j] * 4 + c];
                add4(a0, unp(v));
            }
            add4(a0, a1);
            float inv = 1.0f / (float)(dg > 0 ? dg : 1);
            mm[nl * (HID + 1) + c * 4 + 0] = a0.x * inv;
            mm[nl * (HID + 1) + c * 4 + 1] = a0.y * inv;
            mm[nl * (HID + 1) + c * 4 + 2] = a0.z * inv;
            mm[nl * (HID + 1) + c * 4 + 3] = a0.w * inv;
        }
    }
    __syncthreads();

    // epilogue: slot (node, c) computes outputs o = c*8 .. c*8+7
    {
        int nl = tid >> 2, c = tid & 3;
        int node = b * BNODES + nl;
        if (node >= N) return;

        float m[HID];
#pragma unroll
        for (int k = 0; k < HID; k++) m[k] = mm[nl * (HID + 1) + k];

        float hr[HID];
        const uint4* hp = (const uint4*)(hb + (size_t)node * 8);
        uint4 u0 = hp[0], u1 = hp[1];
        hr[0] = lo2f(u0.x); hr[1] = hi2f(u0.x); hr[2] = lo2f(u0.y); hr[3] = hi2f(u0.y);
        hr[4] = lo2f(u0.z); hr[5] = hi2f(u0.z); hr[6] = lo2f(u0.w); hr[7] = hi2f(u0.w);
        hr[8] = lo2f(u1.x); hr[9] = hi2f(u1.x); hr[10] = lo2f(u1.y); hr[11] = hi2f(u1.y);
        hr[12] = lo2f(u1.z); hr[13] = hi2f(u1.z); hr[14] = lo2f(u1.w); hr[15] = hi2f(u1.w);

        float a[8];
#pragma unroll
        for (int jj = 0; jj < 8; jj++) {
            int o = c * 8 + jj;
            float s = bs[o];
#pragma unroll
            for (int k = 0; k < HID; k++)
                s += m[k] * Wl[o * WS2 + k] + hr[k] * Wr[o * WS2 + k];
            a[jj] = s;
        }
        float4* op = (float4*)(out + (size_t)node * F_IN + c * 8);
        op[0] = make_float4(a[0], a[1], a[2], a[3]);
        op[1] = make_float4(a[4], a[5], a[6], a[7]);
    }
}

extern "C" void kernel_launch(void* const* d_in, const int* in_sizes, int n_in,
                              void* d_out, int out_size, void* d_ws, size_t ws_size,
                              hipStream_t stream) {
    const float* x    = (const float*)d_in[0];
    const int*   ei   = (const int*)d_in[1];   // [2, E] int32
    const float* W1_l = (const float*)d_in[2];
    const float* b1   = (const float*)d_in[3];
    const float* W1_r = (const float*)d_in[4];
    const float* W2_l = (const float*)d_in[5];
    const float* b2   = (const float*)d_in[6];
    const float* W2_r = (const float*)d_in[7];
    float* out = (float*)d_out;

    const int N = in_sizes[0] / F_IN;
    const int E = in_sizes[1] / 2;
    const int nbuckets = (N + BNODES - 1) >> BSHIFT;     // 1563 for N=100000

    int* bucketCursor = (int*)d_ws;                        // [NBINS]
    unsigned* bucketBuf = (unsigned*)(bucketCursor + NBINS);// [nbuckets * CAP]
    unsigned* y1b = bucketBuf + (size_t)nbuckets * CAP;    // [N * 8]  bf16 packed
    unsigned* hb  = y1b + (size_t)N * 8;                   // [N * 8]  bf16 packed
    int* meta = (int*)(hb + (size_t)N * 8);                // [nbuckets * 128]
    float* y1r = (float*)(meta + (size_t)nbuckets * 128);  // [N * 16] fp32

    hipMemsetAsync(bucketCursor, 0, NBINS * sizeof(int), stream);

    const int nodeBlocks = (N + 255) / 256;                // 391
    const int partBlocks = (E + CHUNK - 1) / CHUNK;        // 196

    k_pre<<<nodeBlocks + partBlocks, 256, 0, stream>>>(x, W1_l, b1, W1_r,
                                                       y1b, y1r, ei,
                                                       bucketCursor, bucketBuf,
                                                       N, E, nodeBlocks);
    k_agg1f<<<nbuckets, 256, 0, stream>>>(y1b, y1r, bucketBuf, bucketCursor,
                                          hb, meta, N);
    k_l2f<<<nbuckets, 256, 0, stream>>>(hb, bucketBuf, bucketCursor, meta,
                                        W2_l, b2, W2_r, out, N);
}